// Round 1
// baseline (507.795 us; speedup 1.0000x reference)
//
#include <hip/hip_runtime.h>
#include <math.h>

#define BB  16
#define TT  12
#define T2C 10
#define NN  300
#define DD  64
#define M3  900   // 3*NN

#define TM 64
#define TK 64
#define QS_STRIDE (DD + 4)   // pad to break stride-64 bank aliasing
#define ST_STRIDE (TM + 4)

// ---------------------------------------------------------------------------
// Kernel A: invn[row] = 1 / max(||feat[row]*sigmoid(weights)||, 1e-12)
// also writes sigw[c] = sigmoid(weights[c])
// ---------------------------------------------------------------------------
__global__ __launch_bounds__(256) void k_norm(const float* __restrict__ feat,
                                              const float* __restrict__ weights,
                                              float* __restrict__ sigw,
                                              float* __restrict__ invn,
                                              int nrows) {
    int wave = threadIdx.x >> 6;
    int lane = threadIdx.x & 63;
    int row  = blockIdx.x * 4 + wave;
    float w  = weights[lane];
    float sg = 1.0f / (1.0f + expf(-w));
    if (blockIdx.x == 0 && wave == 0) sigw[lane] = sg;
    if (row < nrows) {
        float x = feat[(size_t)row * DD + lane] * sg;
        float ss = x * x;
        #pragma unroll
        for (int off = 32; off > 0; off >>= 1) ss += __shfl_xor(ss, off, 64);
        float nrm = sqrtf(ss);
        invn[row] = 1.0f / fmaxf(nrm, 1e-12f);
    }
}

// ---------------------------------------------------------------------------
// Kernel B: per (b,t2) window (grid = B*T2*5 blocks; 5 row-blocks of 64):
//   S = Q K^T  (Q = wf rows of t2+2 block, K = wf rows t2..t2+2 = 900 contig)
//   aggU = S V (V = raw feat rows, same 900)  ; deg = rowsum(S)
//   agg = aggU * (deg==0 ? 0 : 1/deg)   -> written to d_out (agg-sized)
// wf rows are rebuilt on the fly: feat * sigw * invn.
// ---------------------------------------------------------------------------
__global__ __launch_bounds__(256) void k_agg(const float* __restrict__ feat,
                                             const float* __restrict__ sigw,
                                             const float* __restrict__ invn,
                                             float* __restrict__ agg) {
    __shared__ float Qs[TM][QS_STRIDE];
    __shared__ float KVs[TK][QS_STRIDE];
    __shared__ float St[TK][ST_STRIDE];
    __shared__ float degs[TM];

    int blk = blockIdx.x;
    int rb  = blk % 5;
    int w   = blk / 5;
    int t2  = w % T2C;
    int b   = w / T2C;
    int n0  = rb * TM;
    int tid = threadIdx.x;
    int tx  = tid & 15;   // 0..15  (col groups)
    int ty  = tid >> 4;   // 0..15  (row groups)

    int qrow0 = (b * TT + (t2 + 2)) * NN;  // global row of Q block
    int krow0 = (b * TT + t2) * NN;        // global row of 900-row K/V panel

    // ---- stage Q (scaled + normalized), zero-pad rows >= NN ----
    for (int i = tid; i < TM * (DD / 4); i += 256) {
        int r = i / (DD / 4), c4 = i % (DD / 4);
        float4 v = make_float4(0.f, 0.f, 0.f, 0.f);
        if (n0 + r < NN) {
            int gr = qrow0 + n0 + r;
            float4 f  = ((const float4*)(feat + (size_t)gr * DD))[c4];
            float4 sg = ((const float4*)sigw)[c4];
            float  in = invn[gr];
            v.x = f.x * sg.x * in; v.y = f.y * sg.y * in;
            v.z = f.z * sg.z * in; v.w = f.w * sg.w * in;
        }
        ((float4*)&Qs[r][0])[c4] = v;
    }

    float acc[4][4];
    #pragma unroll
    for (int i = 0; i < 4; i++) { acc[i][0]=0.f; acc[i][1]=0.f; acc[i][2]=0.f; acc[i][3]=0.f; }
    float dacc[4] = {0.f, 0.f, 0.f, 0.f};

    for (int kt = 0; kt < 15; kt++) {
        int m0 = kt * TK;
        __syncthreads();                       // prev phase2 done with KVs/St
        // ---- stage K tile (scaled wf), zero-pad m >= 900 ----
        for (int i = tid; i < TK * (DD / 4); i += 256) {
            int r = i / (DD / 4), c4 = i % (DD / 4);
            float4 v = make_float4(0.f, 0.f, 0.f, 0.f);
            if (m0 + r < M3) {
                int gr = krow0 + m0 + r;
                float4 f  = ((const float4*)(feat + (size_t)gr * DD))[c4];
                float4 sg = ((const float4*)sigw)[c4];
                float  in = invn[gr];
                v.x = f.x * sg.x * in; v.y = f.y * sg.y * in;
                v.z = f.z * sg.z * in; v.w = f.w * sg.w * in;
            }
            ((float4*)&KVs[r][0])[c4] = v;
        }
        __syncthreads();

        // ---- phase 1: s[i][j] = dot(Q[4ty+i], K[4tx+j]) over D=64 ----
        float s[4][4];
        #pragma unroll
        for (int i = 0; i < 4; i++) { s[i][0]=0.f; s[i][1]=0.f; s[i][2]=0.f; s[i][3]=0.f; }
        #pragma unroll 4
        for (int k = 0; k < DD; k += 4) {
            float4 q[4], kk[4];
            #pragma unroll
            for (int i = 0; i < 4; i++) q[i]  = *(const float4*)&Qs[4*ty + i][k];
            #pragma unroll
            for (int j = 0; j < 4; j++) kk[j] = *(const float4*)&KVs[4*tx + j][k];
            #pragma unroll
            for (int i = 0; i < 4; i++)
                #pragma unroll
                for (int j = 0; j < 4; j++)
                    s[i][j] += q[i].x*kk[j].x + q[i].y*kk[j].y
                             + q[i].z*kk[j].z + q[i].w*kk[j].w;
        }
        // write S transposed: St[m][n]  (float4 over 4 rows)
        #pragma unroll
        for (int j = 0; j < 4; j++)
            *(float4*)&St[4*tx + j][4*ty] = make_float4(s[0][j], s[1][j], s[2][j], s[3][j]);
        __syncthreads();                       // K reads + St writes done

        // ---- stage V tile (raw feat) into same buffer ----
        for (int i = tid; i < TK * (DD / 4); i += 256) {
            int r = i / (DD / 4), c4 = i % (DD / 4);
            float4 v = make_float4(0.f, 0.f, 0.f, 0.f);
            if (m0 + r < M3)
                v = ((const float4*)(feat + (size_t)(krow0 + m0 + r) * DD))[c4];
            ((float4*)&KVs[r][0])[c4] = v;
        }
        __syncthreads();

        // ---- phase 2: acc[i][j] += s[row 4ty+i][m] * V[m][4tx+j]; deg too ----
        #pragma unroll 4
        for (int mm = 0; mm < TK; mm++) {
            float4 sv = *(const float4*)&St[mm][4*ty];   // rows 4ty..4ty+3 at col mm
            float4 vv = *(const float4*)&KVs[mm][4*tx];  // V[mm][4tx..4tx+3]
            acc[0][0] += sv.x * vv.x; acc[0][1] += sv.x * vv.y;
            acc[0][2] += sv.x * vv.z; acc[0][3] += sv.x * vv.w;
            acc[1][0] += sv.y * vv.x; acc[1][1] += sv.y * vv.y;
            acc[1][2] += sv.y * vv.z; acc[1][3] += sv.y * vv.w;
            acc[2][0] += sv.z * vv.x; acc[2][1] += sv.z * vv.y;
            acc[2][2] += sv.z * vv.z; acc[2][3] += sv.z * vv.w;
            acc[3][0] += sv.w * vv.x; acc[3][1] += sv.w * vv.y;
            acc[3][2] += sv.w * vv.z; acc[3][3] += sv.w * vv.w;
            if (tx == 0) {
                dacc[0] += sv.x; dacc[1] += sv.y; dacc[2] += sv.z; dacc[3] += sv.w;
            }
        }
    }

    __syncthreads();
    if (tx == 0) {
        degs[4*ty + 0] = dacc[0]; degs[4*ty + 1] = dacc[1];
        degs[4*ty + 2] = dacc[2]; degs[4*ty + 3] = dacc[3];
    }
    __syncthreads();

    float* obase = agg + (size_t)(b * T2C + t2) * NN * DD;
    #pragma unroll
    for (int i = 0; i < 4; i++) {
        int n = n0 + 4*ty + i;
        if (n < NN) {
            float dg   = degs[4*ty + i];
            float dinv = (dg == 0.0f) ? 0.0f : 1.0f / dg;
            float4 o = make_float4(acc[i][0]*dinv, acc[i][1]*dinv,
                                   acc[i][2]*dinv, acc[i][3]*dinv);
            *(float4*)(obase + (size_t)n * DD + 4*tx) = o;
        }
    }
}

// ---------------------------------------------------------------------------
// Kernel C: per row (one wave each):
//   h = relu(agg@w1 + b1); o = h@w2 + b2; s = feat[:,2:] + o; out = LN(s)
// agg is read from d_out and overwritten in place (1:1 row mapping, safe).
// ---------------------------------------------------------------------------
__global__ __launch_bounds__(256) void k_ffn(const float* __restrict__ aggin,
                                             const float* __restrict__ feat,
                                             const float* __restrict__ w1,
                                             const float* __restrict__ b1,
                                             const float* __restrict__ w2,
                                             const float* __restrict__ b2,
                                             const float* __restrict__ gamma,
                                             const float* __restrict__ beta,
                                             float* __restrict__ out) {
    __shared__ float w1s[DD * DD];
    __shared__ float w2s[DD * DD];
    int tid = threadIdx.x;
    for (int i = tid; i < DD * DD; i += 256) { w1s[i] = w1[i]; w2s[i] = w2[i]; }
    __syncthreads();

    int wave = tid >> 6, lane = tid & 63;
    int row = blockIdx.x * 4 + wave;          // grid sized exactly: no guard needed
    int n   = row % NN;
    int bt  = row / NN;
    int t2  = bt % T2C;
    int b   = bt / T2C;

    float a  = aggin[(size_t)row * DD + lane];
    float fv = feat[((size_t)(b * TT + t2 + 2) * NN + n) * DD + lane];

    float h0 = 0.f, h1 = 0.f, h2 = 0.f, h3 = 0.f;
    #pragma unroll
    for (int k = 0; k < DD; k += 4) {
        h0 += __shfl(a, k + 0, 64) * w1s[(k + 0) * DD + lane];
        h1 += __shfl(a, k + 1, 64) * w1s[(k + 1) * DD + lane];
        h2 += __shfl(a, k + 2, 64) * w1s[(k + 2) * DD + lane];
        h3 += __shfl(a, k + 3, 64) * w1s[(k + 3) * DD + lane];
    }
    float h = fmaxf((h0 + h1) + (h2 + h3) + b1[lane], 0.0f);

    float o0 = 0.f, o1 = 0.f, o2 = 0.f, o3 = 0.f;
    #pragma unroll
    for (int k = 0; k < DD; k += 4) {
        o0 += __shfl(h, k + 0, 64) * w2s[(k + 0) * DD + lane];
        o1 += __shfl(h, k + 1, 64) * w2s[(k + 1) * DD + lane];
        o2 += __shfl(h, k + 2, 64) * w2s[(k + 2) * DD + lane];
        o3 += __shfl(h, k + 3, 64) * w2s[(k + 3) * DD + lane];
    }
    float s = fv + (o0 + o1) + (o2 + o3) + b2[lane];

    float sum = s;
    #pragma unroll
    for (int off = 32; off > 0; off >>= 1) sum += __shfl_xor(sum, off, 64);
    float mu = sum * (1.0f / 64.0f);
    float d  = s - mu;
    float v2 = d * d;
    #pragma unroll
    for (int off = 32; off > 0; off >>= 1) v2 += __shfl_xor(v2, off, 64);
    float var = v2 * (1.0f / 64.0f);

    out[(size_t)row * DD + lane] = d * rsqrtf(var + 1e-5f) * gamma[lane] + beta[lane];
}

// ---------------------------------------------------------------------------
extern "C" void kernel_launch(void* const* d_in, const int* in_sizes, int n_in,
                              void* d_out, int out_size, void* d_ws, size_t ws_size,
                              hipStream_t stream) {
    const float* feat    = (const float*)d_in[0];
    const float* weights = (const float*)d_in[1];
    const float* w1      = (const float*)d_in[2];
    const float* b1      = (const float*)d_in[3];
    const float* w2      = (const float*)d_in[4];
    const float* b2      = (const float*)d_in[5];
    const float* gamma   = (const float*)d_in[6];
    const float* beta    = (const float*)d_in[7];
    float* out = (float*)d_out;

    float* sigw = (float*)d_ws;        // 64 floats
    float* invn = sigw + 64;           // B*T*N = 57600 floats

    int nrows = BB * TT * NN;          // 57600
    k_norm<<<nrows / 4, 256, 0, stream>>>(feat, weights, sigw, invn, nrows);
    k_agg<<<BB * T2C * 5, 256, 0, stream>>>(feat, sigw, invn, out);
    k_ffn<<<(BB * T2C * NN) / 4, 256, 0, stream>>>(out, feat, w1, b1, w2, b2,
                                                   gamma, beta, out);
}

// Round 3
// 207.051 us; speedup vs baseline: 2.4525x; 2.4525x over previous
//
#include <hip/hip_runtime.h>
#include <math.h>

#define BB  16
#define TT  12
#define T2C 10
#define NN  300
#define DD  64
#define M3  900   // 3*NN
#define NW  (BB*T2C)

typedef _Float16 f16;
typedef __attribute__((ext_vector_type(8)))  _Float16 f16x8;
typedef __attribute__((ext_vector_type(16))) float    f32x16;

#define KS 72   // fp16 row stride (144 B, 16B-aligned) for K / Vt / S / A / W / H tiles

static __device__ inline unsigned pk2(f16 a, f16 b) {
    union { f16 h[2]; unsigned u; } x; x.h[0] = a; x.h[1] = b; return x.u;
}

// ---------------------------------------------------------------------------
// invn[row] = 1/max(||feat[row]*sigmoid(w)||,1e-12); sigw = sigmoid(w)
// ---------------------------------------------------------------------------
__global__ __launch_bounds__(256) void k_norm(const float* __restrict__ feat,
                                              const float* __restrict__ weights,
                                              float* __restrict__ sigw,
                                              float* __restrict__ invn) {
    int wave = threadIdx.x >> 6, lane = threadIdx.x & 63;
    int row  = blockIdx.x * 4 + wave;
    float sg = 1.0f / (1.0f + expf(-weights[lane]));
    if (blockIdx.x == 0 && wave == 0) sigw[lane] = sg;
    float x = feat[(size_t)row * DD + lane] * sg;
    float ss = x * x;
    #pragma unroll
    for (int off = 32; off > 0; off >>= 1) ss += __shfl_xor(ss, off, 64);
    invn[row] = 1.0f / fmaxf(sqrtf(ss), 1e-12f);
}

// ---------------------------------------------------------------------------
// ksum[window][d] = sigw[d] * sum_{m<900} feat[krow0+m][d]*invn[krow0+m]
// (fp32-exact row-sum basis: deg[n] = q_n . ksum, immune to fp16 S noise)
// ---------------------------------------------------------------------------
__global__ __launch_bounds__(256) void k_ksum(const float* __restrict__ feat,
                                              const float* __restrict__ sigw,
                                              const float* __restrict__ invn,
                                              float* __restrict__ ksum) {
    __shared__ float part[4][DD];
    int wdw = blockIdx.x;
    int t2 = wdw % T2C, b = wdw / T2C;
    int krow0 = (b * TT + t2) * NN;
    int d = threadIdx.x & 63, g = threadIdx.x >> 6;
    float acc = 0.f;
    for (int m = g; m < M3; m += 4) {
        int gr = krow0 + m;
        acc += feat[(size_t)gr * DD + d] * invn[gr];
    }
    part[g][d] = acc;
    __syncthreads();
    if (g == 0)
        ksum[(size_t)wdw * DD + d] =
            (part[0][d] + part[1][d] + part[2][d] + part[3][d]) * sigw[d];
}

// ---------------------------------------------------------------------------
// k_agg (MFMA fp16): per (window, 64-row block):
//   phase1: S^T tile = K_tile(32x64) . Q^T  -> S_lds[n][m] fp16
//   phase2: acc(n,d) += S(n,m) . V(m,d)     (V^T staged fp16)
//   deg = q.ksum (fp32), agg = acc*dinv -> d_out (fp32; may be huge, fp32 ok)
// ---------------------------------------------------------------------------
__global__ __launch_bounds__(256) void k_agg(const float* __restrict__ feat,
                                             const float* __restrict__ sigw,
                                             const float* __restrict__ invn,
                                             const float* __restrict__ ksum,
                                             float* __restrict__ agg) {
    __shared__ f16 Kf[64 * KS];   // wf rows [m][k]
    __shared__ f16 Vt[64 * KS];   // raw feat transposed [d][m]
    __shared__ f16 Sl[64 * KS];   // S [n][m]
    __shared__ float degp[64][4];
    __shared__ float degs[64];

    int blk = blockIdx.x;
    int rb = blk % 5, wdw = blk / 5;
    int t2 = wdw % T2C, b = wdw / T2C;
    int n0 = rb * 64;
    int qrow0 = (b * TT + t2 + 2) * NN;
    int krow0 = (b * TT + t2) * NN;
    int tid = threadIdx.x;
    int wv = tid >> 6, lane = tid & 63;
    int l31 = lane & 31, lh = lane >> 5;
    int nt = wv & 1;   // phase1 n-block == phase2 row-block
    int mt = wv >> 1;  // phase1 m-tile  == phase2 d-block

    // ---- deg partials: deg[n] = (feat[n]*sigw . ksum) * invn[n] ----
    {
        int r = tid >> 2, qd = (tid & 3) * 16;
        float p = 0.f;
        if (n0 + r < NN) {
            int gr = qrow0 + n0 + r;
            float in = invn[gr];
            const float4* f4 = (const float4*)(feat + (size_t)gr * DD + qd);
            const float4* s4 = (const float4*)(sigw + qd);
            const float4* k4 = (const float4*)(ksum + (size_t)wdw * DD + qd);
            #pragma unroll
            for (int i = 0; i < 4; i++) {
                float4 f = f4[i], s = s4[i], k = k4[i];
                p += f.x * s.x * k.x + f.y * s.y * k.y + f.z * s.z * k.z + f.w * s.w * k.w;
            }
            p *= in;
        }
        degp[r][tid & 3] = p;
    }

    // ---- Q B-frags in registers (4 kd-steps), row = n0 + nt*32 + l31 ----
    f16x8 qf[4];
    {
        int nloc = n0 + nt * 32 + l31;
        bool ok = nloc < NN;
        int gr = qrow0 + nloc;
        float in = ok ? invn[gr] : 0.f;
        #pragma unroll
        for (int ks = 0; ks < 4; ks++) {
            int c0 = ks * 16 + 8 * lh;
            f16x8 q;
            #pragma unroll
            for (int i = 0; i < 8; i++) q[i] = (f16)0.f;
            if (ok) {
                float4 f0 = *(const float4*)(feat + (size_t)gr * DD + c0);
                float4 f1 = *(const float4*)(feat + (size_t)gr * DD + c0 + 4);
                float4 s0 = *(const float4*)(sigw + c0);
                float4 s1 = *(const float4*)(sigw + c0 + 4);
                q[0] = (f16)(f0.x * s0.x * in); q[1] = (f16)(f0.y * s0.y * in);
                q[2] = (f16)(f0.z * s0.z * in); q[3] = (f16)(f0.w * s0.w * in);
                q[4] = (f16)(f1.x * s1.x * in); q[5] = (f16)(f1.y * s1.y * in);
                q[6] = (f16)(f1.z * s1.z * in); q[7] = (f16)(f1.w * s1.w * in);
            }
            qf[ks] = q;
        }
    }
    __syncthreads();
    if (tid < 64)
        degs[tid] = degp[tid][0] + degp[tid][1] + degp[tid][2] + degp[tid][3];

    f32x16 acc;
    #pragma unroll
    for (int i = 0; i < 16; i++) acc[i] = 0.f;

    int mrow_s = (tid & 31) * 2;     // staging m-pair
    int dblk_s = (tid >> 5) * 8;     // staging 8-col block

    for (int kt = 0; kt < 15; kt++) {
        int m0 = kt * 64;
        __syncthreads();   // prev phase2 done with Kf/Vt/Sl

        // ---- stage Kf (wf fp16) + Vt (raw fp16 transposed) ----
        f16 vv[2][8];
        #pragma unroll
        for (int pi = 0; pi < 2; pi++) {
            int mloc = mrow_s + pi, gm = m0 + mloc;
            float4 fa = make_float4(0, 0, 0, 0), fb = make_float4(0, 0, 0, 0);
            float in = 0.f;
            if (gm < M3) {
                int gr = krow0 + gm;
                in = invn[gr];
                fa = *(const float4*)(feat + (size_t)gr * DD + dblk_s);
                fb = *(const float4*)(feat + (size_t)gr * DD + dblk_s + 4);
            }
            float4 s0 = *(const float4*)(sigw + dblk_s);
            float4 s1 = *(const float4*)(sigw + dblk_s + 4);
            f16x8 kr;
            kr[0] = (f16)(fa.x * s0.x * in); kr[1] = (f16)(fa.y * s0.y * in);
            kr[2] = (f16)(fa.z * s0.z * in); kr[3] = (f16)(fa.w * s0.w * in);
            kr[4] = (f16)(fb.x * s1.x * in); kr[5] = (f16)(fb.y * s1.y * in);
            kr[6] = (f16)(fb.z * s1.z * in); kr[7] = (f16)(fb.w * s1.w * in);
            *(f16x8*)&Kf[mloc * KS + dblk_s] = kr;
            vv[pi][0] = (f16)fa.x; vv[pi][1] = (f16)fa.y; vv[pi][2] = (f16)fa.z; vv[pi][3] = (f16)fa.w;
            vv[pi][4] = (f16)fb.x; vv[pi][5] = (f16)fb.y; vv[pi][6] = (f16)fb.z; vv[pi][7] = (f16)fb.w;
        }
        #pragma unroll
        for (int i = 0; i < 8; i++)
            *(unsigned*)&Vt[(dblk_s + i) * KS + mrow_s] = pk2(vv[0][i], vv[1][i]);
        __syncthreads();

        // ---- phase1: S^T tile (m-rows mt*32.., n-cols nt*32..) ----
        f32x16 c1;
        #pragma unroll
        for (int i = 0; i < 16; i++) c1[i] = 0.f;
        #pragma unroll
        for (int ks = 0; ks < 4; ks++) {
            f16x8 af = *(const f16x8*)&Kf[(mt * 32 + l31) * KS + ks * 16 + 8 * lh];
            c1 = __builtin_amdgcn_mfma_f32_32x32x16_f16(af, qf[ks], c1, 0, 0, 0);
        }
        // write S_lds[n][m]: C rows are m-runs of 4 -> b64
        #pragma unroll
        for (int g = 0; g < 4; g++) {
            union { f16 h[4]; uint2 u; } p;
            p.h[0] = (f16)c1[4 * g + 0]; p.h[1] = (f16)c1[4 * g + 1];
            p.h[2] = (f16)c1[4 * g + 2]; p.h[3] = (f16)c1[4 * g + 3];
            *(uint2*)&Sl[(nt * 32 + l31) * KS + mt * 32 + 8 * g + 4 * lh] = p.u;
        }
        __syncthreads();

        // ---- phase2: acc(n-block nt, d-block mt) += S . V ----
        #pragma unroll
        for (int ms = 0; ms < 4; ms++) {
            f16x8 sa = *(const f16x8*)&Sl[(nt * 32 + l31) * KS + ms * 16 + 8 * lh];
            f16x8 vb = *(const f16x8*)&Vt[(mt * 32 + l31) * KS + ms * 16 + 8 * lh];
            acc = __builtin_amdgcn_mfma_f32_32x32x16_f16(sa, vb, acc, 0, 0, 0);
        }
    }

    __syncthreads();
    float* ob = agg + (size_t)(b * T2C + t2) * NN * DD;
    int dcol = mt * 32 + l31;
    #pragma unroll
    for (int g = 0; g < 4; g++) {
        #pragma unroll
        for (int i = 0; i < 4; i++) {
            int rl = nt * 32 + 8 * g + 4 * lh + i;
            int n = n0 + rl;
            if (n < NN) {
                float dg = degs[rl];
                float dinv = (dg == 0.f) ? 0.f : 1.f / dg;
                ob[(size_t)n * DD + dcol] = acc[4 * g + i] * dinv;
            }
        }
    }
}

// ---------------------------------------------------------------------------
// k_ffn (MFMA fp16) with per-row power-of-2 scaling (overflow-proof):
//   s_n = 2^-e so max|agg_n * s_n| in (0.5, 1]
//   h_s = relu(A_s w1 + s_n b1) = s_n * h   (exact: relu pos-homogeneous)
//   o   = (h_s w2) / s_n + b2   (fp32 epilogue), + residual + LayerNorm
// ---------------------------------------------------------------------------
__global__ __launch_bounds__(256) void k_ffn(const float* __restrict__ aggin,
                                             const float* __restrict__ feat,
                                             const float* __restrict__ w1,
                                             const float* __restrict__ b1,
                                             const float* __restrict__ w2,
                                             const float* __restrict__ b2,
                                             const float* __restrict__ gamma,
                                             const float* __restrict__ beta,
                                             float* __restrict__ out) {
    __shared__ f16 Al[64 * KS];    // a_scaled [row][k]
    __shared__ f16 W1t[64 * KS];   // w1^T [n][k]
    __shared__ f16 W2t[64 * KS];
    __shared__ f16 Hl[64 * KS];    // h_s [row][hcol]
    __shared__ float Ol[64 * 68];  // o_s [row][col] fp32
    __shared__ float red[64][4][2];
    __shared__ float rmax[64][4];
    __shared__ float scls[64];     // s_n
    __shared__ float isls[64];     // 1/s_n (exact pow2)

    int tid = threadIdx.x;
    int wv = tid >> 6, lane = tid & 63;
    int l31 = lane & 31, lh = lane >> 5;
    int row0 = blockIdx.x * 64;
    int r = tid >> 2, q = tid & 3, c0 = q * 16;

    // ---- read agg fp32, per-row absmax ----
    float av[16];
    {
        const float4* src = (const float4*)(aggin + (size_t)(row0 + r) * DD + c0);
        float mx = 0.f;
        #pragma unroll
        for (int i = 0; i < 4; i++) {
            float4 f = src[i];
            av[4 * i + 0] = f.x; av[4 * i + 1] = f.y;
            av[4 * i + 2] = f.z; av[4 * i + 3] = f.w;
            mx = fmaxf(mx, fmaxf(fmaxf(fabsf(f.x), fabsf(f.y)),
                                 fmaxf(fabsf(f.z), fabsf(f.w))));
        }
        rmax[r][q] = mx;
    }
    // ---- stage W1t/W2t transposed via k-pair half2 writes ----
    {
        int k0 = (tid & 31) * 2, nb = (tid >> 5) * 8;
        #pragma unroll
        for (int i = 0; i < 2; i++) {
            float4 ra = *(const float4*)(w1 + (size_t)k0 * DD + nb + 4 * i);
            float4 rb = *(const float4*)(w1 + (size_t)(k0 + 1) * DD + nb + 4 * i);
            *(unsigned*)&W1t[(nb + 4 * i + 0) * KS + k0] = pk2((f16)ra.x, (f16)rb.x);
            *(unsigned*)&W1t[(nb + 4 * i + 1) * KS + k0] = pk2((f16)ra.y, (f16)rb.y);
            *(unsigned*)&W1t[(nb + 4 * i + 2) * KS + k0] = pk2((f16)ra.z, (f16)rb.z);
            *(unsigned*)&W1t[(nb + 4 * i + 3) * KS + k0] = pk2((f16)ra.w, (f16)rb.w);
            float4 rc = *(const float4*)(w2 + (size_t)k0 * DD + nb + 4 * i);
            float4 rd = *(const float4*)(w2 + (size_t)(k0 + 1) * DD + nb + 4 * i);
            *(unsigned*)&W2t[(nb + 4 * i + 0) * KS + k0] = pk2((f16)rc.x, (f16)rd.x);
            *(unsigned*)&W2t[(nb + 4 * i + 1) * KS + k0] = pk2((f16)rc.y, (f16)rd.y);
            *(unsigned*)&W2t[(nb + 4 * i + 2) * KS + k0] = pk2((f16)rc.z, (f16)rd.z);
            *(unsigned*)&W2t[(nb + 4 * i + 3) * KS + k0] = pk2((f16)rc.w, (f16)rd.w);
        }
    }
    __syncthreads();

    // ---- per-row pow2 scale; stage A_s fp16 ----
    {
        float rm = fmaxf(fmaxf(rmax[r][0], rmax[r][1]), fmaxf(rmax[r][2], rmax[r][3]));
        int e = 0;
        frexpf(rm, &e);                       // rm = m*2^e, m in [0.5,1)
        float scl = (rm > 1.f) ? exp2f((float)-e) : 1.f;
        if (q == 0) { scls[r] = scl; isls[r] = (rm > 1.f) ? exp2f((float)e) : 1.f; }
        #pragma unroll
        for (int i = 0; i < 2; i++) {
            f16x8 v;
            #pragma unroll
            for (int j = 0; j < 8; j++) v[j] = (f16)(av[8 * i + j] * scl);
            *(f16x8*)&Al[r * KS + c0 + 8 * i] = v;
        }
    }
    __syncthreads();

    int ct = wv & 1, rt = wv >> 1;   // tile: cols ct*32.., rows rt*32..

    // phase A: h_s^T tile = w1^T . A_s^T  (D[hcol][arow])
    f32x16 hc;
    #pragma unroll
    for (int i = 0; i < 16; i++) hc[i] = 0.f;
    #pragma unroll
    for (int ks = 0; ks < 4; ks++) {
        f16x8 af = *(const f16x8*)&W1t[(ct * 32 + l31) * KS + ks * 16 + 8 * lh];
        f16x8 bf = *(const f16x8*)&Al[(rt * 32 + l31) * KS + ks * 16 + 8 * lh];
        hc = __builtin_amdgcn_mfma_f32_32x32x16_f16(af, bf, hc, 0, 0, 0);
    }
    {
        float sA = scls[rt * 32 + l31];   // scale of this lane's a-row (D col)
        #pragma unroll
        for (int g = 0; g < 4; g++) {
            union { f16 h[4]; uint2 u; } p;
            #pragma unroll
            for (int i = 0; i < 4; i++) {
                int hcol = ct * 32 + 8 * g + 4 * lh + i;
                p.h[i] = (f16)fmaxf(hc[4 * g + i] + sA * b1[hcol], 0.f);
            }
            *(uint2*)&Hl[(rt * 32 + l31) * KS + ct * 32 + 8 * g + 4 * lh] = p.u;
        }
    }
    __syncthreads();

    // phase B: o_s^T tile = w2^T . h_s^T
    f32x16 oc;
    #pragma unroll
    for (int i = 0; i < 16; i++) oc[i] = 0.f;
    #pragma unroll
    for (int ks = 0; ks < 4; ks++) {
        f16x8 af = *(const f16x8*)&W2t[(ct * 32 + l31) * KS + ks * 16 + 8 * lh];
        f16x8 bf = *(const f16x8*)&Hl[(rt * 32 + l31) * KS + ks * 16 + 8 * lh];
        oc = __builtin_amdgcn_mfma_f32_32x32x16_f16(af, bf, oc, 0, 0, 0);
    }
    #pragma unroll
    for (int g = 0; g < 4; g++) {
        float4 o4 = make_float4(oc[4 * g + 0], oc[4 * g + 1], oc[4 * g + 2], oc[4 * g + 3]);
        *(float4*)&Ol[(rt * 32 + l31) * 68 + ct * 32 + 8 * g + 4 * lh] = o4;
    }
    __syncthreads();

    // epilogue: s = o_s/s_n + b2 + feat_residual; LayerNorm
    size_t grow = row0 + r;
    int n = (int)(grow % NN);
    int bt = (int)(grow / NN);
    int t2 = bt % T2C, bb = bt / T2C;
    size_t frow = (size_t)(bb * TT + t2 + 2) * NN + n;
    float is = isls[r];
    float v[16];
    float sum = 0.f;
    #pragma unroll
    for (int i = 0; i < 16; i++) {
        int c = c0 + i;
        float x = Ol[r * 68 + c] * is + b2[c] + feat[frow * DD + c];
        v[i] = x; sum += x;
    }
    red[r][q][0] = sum;
    __syncthreads();
    float mu = (red[r][0][0] + red[r][1][0] + red[r][2][0] + red[r][3][0]) * (1.f / 64.f);
    float s2 = 0.f;
    #pragma unroll
    for (int i = 0; i < 16; i++) { float d = v[i] - mu; s2 += d * d; }
    red[r][q][1] = s2;
    __syncthreads();
    float var = (red[r][0][1] + red[r][1][1] + red[r][2][1] + red[r][3][1]) * (1.f / 64.f);
    float rs = rsqrtf(var + 1e-5f);
    #pragma unroll
    for (int i4 = 0; i4 < 4; i4++) {
        int c = c0 + 4 * i4;
        float4 g4 = *(const float4*)(gamma + c);
        float4 be = *(const float4*)(beta + c);
        float4 o4;
        o4.x = (v[4 * i4 + 0] - mu) * rs * g4.x + be.x;
        o4.y = (v[4 * i4 + 1] - mu) * rs * g4.y + be.y;
        o4.z = (v[4 * i4 + 2] - mu) * rs * g4.z + be.z;
        o4.w = (v[4 * i4 + 3] - mu) * rs * g4.w + be.w;
        *(float4*)(out + grow * DD + c) = o4;
    }
}

// ---------------------------------------------------------------------------
extern "C" void kernel_launch(void* const* d_in, const int* in_sizes, int n_in,
                              void* d_out, int out_size, void* d_ws, size_t ws_size,
                              hipStream_t stream) {
    const float* feat    = (const float*)d_in[0];
    const float* weights = (const float*)d_in[1];
    const float* w1      = (const float*)d_in[2];
    const float* b1      = (const float*)d_in[3];
    const float* w2      = (const float*)d_in[4];
    const float* b2      = (const float*)d_in[5];
    const float* gamma   = (const float*)d_in[6];
    const float* beta    = (const float*)d_in[7];
    float* out = (float*)d_out;

    float* sigw = (float*)d_ws;            // 64
    float* invn = sigw + 64;               // 57600
    float* ksum = invn + BB * TT * NN;     // 160*64

    int nrows = BB * TT * NN;
    k_norm<<<nrows / 4, 256, 0, stream>>>(feat, weights, sigw, invn);
    k_ksum<<<NW, 256, 0, stream>>>(feat, sigw, invn, ksum);
    k_agg<<<NW * 5, 256, 0, stream>>>(feat, sigw, invn, ksum, out);
    k_ffn<<<(BB * T2C * NN) / 64, 256, 0, stream>>>(out, feat, w1, b1, w2, b2,
                                                    gamma, beta, out);
}

// Round 4
// 150.767 us; speedup vs baseline: 3.3681x; 1.3733x over previous
//
#include <hip/hip_runtime.h>
#include <math.h>

#define BB  16
#define TT  12
#define T2C 10
#define NN  300
#define DD  64
#define M3  900   // 3*NN
#define NW  (BB*T2C)

typedef _Float16 f16;
typedef __attribute__((ext_vector_type(8)))  _Float16 f16x8;
typedef __attribute__((ext_vector_type(16))) float    f32x16;

#define KS 72   // fp16 row stride (144 B, 16B-aligned) for K / Vt / S / A / W / H tiles

static __device__ inline unsigned pk2(f16 a, f16 b) {
    union { f16 h[2]; unsigned u; } x; x.h[0] = a; x.h[1] = b; return x.u;
}

// ---------------------------------------------------------------------------
// k_prep: fused k_norm + per-timestep ksum basis.
// grid = 192 (b,t) x 5 chunks of 60 rows. Per row: invn via shuffle-reduce
// (stored for k_agg); per (b,t): tsum[bt][d] = sigw[d]*sum_n feat[n][d]*invn[n]
// accumulated via one atomicAdd per lane per block (5 adds/address total).
// ---------------------------------------------------------------------------
__global__ __launch_bounds__(256) void k_prep(const float* __restrict__ feat,
                                              const float* __restrict__ weights,
                                              float* __restrict__ sigw,
                                              float* __restrict__ invn,
                                              float* __restrict__ tsum) {
    __shared__ float part[4][DD];
    int blk = blockIdx.x;
    int bt = blk / 5, ch = blk % 5;
    int row0 = bt * NN + ch * 60;
    int d = threadIdx.x & 63, w = threadIdx.x >> 6;

    float sg = 1.0f / (1.0f + expf(-weights[d]));
    if (blk == 0 && threadIdx.x < 64) sigw[d] = sg;

    float acc = 0.f;
    for (int i = w; i < 60; i += 4) {
        int gr = row0 + i;
        float f = feat[(size_t)gr * DD + d];
        float x = f * sg;
        float ss = x * x;
        #pragma unroll
        for (int off = 32; off > 0; off >>= 1) ss += __shfl_xor(ss, off, 64);
        float in = 1.0f / fmaxf(sqrtf(ss), 1e-12f);
        if (d == 0) invn[gr] = in;
        acc += f * in;
    }
    part[w][d] = acc;
    __syncthreads();
    if (w == 0) {
        float v = (part[0][d] + part[1][d] + part[2][d] + part[3][d]) * sg;
        atomicAdd(&tsum[(size_t)bt * DD + d], v);
    }
}

// ---------------------------------------------------------------------------
// k_agg (MFMA fp16): per (window, 64-row block):
//   phase1: S^T tile = K_tile(32x64) . Q^T  -> S_lds[n][m] fp16
//   phase2: acc(n,d) += S(n,m) . V(m,d)     (V^T staged fp16)
//   deg = q.(tsum[t2]+tsum[t2+1]+tsum[t2+2]) (fp32), agg = acc*dinv -> d_out
// ---------------------------------------------------------------------------
__global__ __launch_bounds__(256) void k_agg(const float* __restrict__ feat,
                                             const float* __restrict__ sigw,
                                             const float* __restrict__ invn,
                                             const float* __restrict__ tsum,
                                             float* __restrict__ agg) {
    __shared__ f16 Kf[64 * KS];   // wf rows [m][k]
    __shared__ f16 Vt[64 * KS];   // raw feat transposed [d][m]
    __shared__ f16 Sl[64 * KS];   // S [n][m]
    __shared__ float degp[64][4];
    __shared__ float degs[64];

    int blk = blockIdx.x;
    int rb = blk % 5, wdw = blk / 5;
    int t2 = wdw % T2C, b = wdw / T2C;
    int n0 = rb * 64;
    int qrow0 = (b * TT + t2 + 2) * NN;
    int krow0 = (b * TT + t2) * NN;
    int tid = threadIdx.x;
    int wv = tid >> 6, lane = tid & 63;
    int l31 = lane & 31, lh = lane >> 5;
    int nt = wv & 1;   // phase1 n-block == phase2 row-block
    int mt = wv >> 1;  // phase1 m-tile  == phase2 d-block

    // ---- deg partials: deg[n] = (feat[n]*sigw . ksum_w) * invn[n] ----
    {
        int r = tid >> 2, qd = (tid & 3) * 16;
        float p = 0.f;
        if (n0 + r < NN) {
            int gr = qrow0 + n0 + r;
            float in = invn[gr];
            const float4* f4 = (const float4*)(feat + (size_t)gr * DD + qd);
            const float4* s4 = (const float4*)(sigw + qd);
            const float4* t4 = (const float4*)(tsum + (size_t)(b * TT + t2) * DD + qd);
            #pragma unroll
            for (int i = 0; i < 4; i++) {
                float4 f = f4[i], s = s4[i];
                float4 k0 = t4[i], k1 = t4[i + 16], k2 = t4[i + 32];
                float kx = k0.x + k1.x + k2.x, ky = k0.y + k1.y + k2.y;
                float kz = k0.z + k1.z + k2.z, kw = k0.w + k1.w + k2.w;
                p += f.x * s.x * kx + f.y * s.y * ky + f.z * s.z * kz + f.w * s.w * kw;
            }
            p *= in;
        }
        degp[r][tid & 3] = p;
    }

    // ---- Q B-frags in registers (4 kd-steps), row = n0 + nt*32 + l31 ----
    f16x8 qf[4];
    {
        int nloc = n0 + nt * 32 + l31;
        bool ok = nloc < NN;
        int gr = qrow0 + nloc;
        float in = ok ? invn[gr] : 0.f;
        #pragma unroll
        for (int ks = 0; ks < 4; ks++) {
            int c0 = ks * 16 + 8 * lh;
            f16x8 q;
            #pragma unroll
            for (int i = 0; i < 8; i++) q[i] = (f16)0.f;
            if (ok) {
                float4 f0 = *(const float4*)(feat + (size_t)gr * DD + c0);
                float4 f1 = *(const float4*)(feat + (size_t)gr * DD + c0 + 4);
                float4 s0 = *(const float4*)(sigw + c0);
                float4 s1 = *(const float4*)(sigw + c0 + 4);
                q[0] = (f16)(f0.x * s0.x * in); q[1] = (f16)(f0.y * s0.y * in);
                q[2] = (f16)(f0.z * s0.z * in); q[3] = (f16)(f0.w * s0.w * in);
                q[4] = (f16)(f1.x * s1.x * in); q[5] = (f16)(f1.y * s1.y * in);
                q[6] = (f16)(f1.z * s1.z * in); q[7] = (f16)(f1.w * s1.w * in);
            }
            qf[ks] = q;
        }
    }
    __syncthreads();
    if (tid < 64)
        degs[tid] = degp[tid][0] + degp[tid][1] + degp[tid][2] + degp[tid][3];

    f32x16 acc;
    #pragma unroll
    for (int i = 0; i < 16; i++) acc[i] = 0.f;

    int mrow_s = (tid & 31) * 2;     // staging m-pair
    int dblk_s = (tid >> 5) * 8;     // staging 8-col block

    for (int kt = 0; kt < 15; kt++) {
        int m0 = kt * 64;
        __syncthreads();   // prev phase2 done with Kf/Vt/Sl

        // ---- stage Kf (wf fp16) + Vt (raw fp16 transposed) ----
        f16 vv[2][8];
        #pragma unroll
        for (int pi = 0; pi < 2; pi++) {
            int mloc = mrow_s + pi, gm = m0 + mloc;
            float4 fa = make_float4(0, 0, 0, 0), fb = make_float4(0, 0, 0, 0);
            float in = 0.f;
            if (gm < M3) {
                int gr = krow0 + gm;
                in = invn[gr];
                fa = *(const float4*)(feat + (size_t)gr * DD + dblk_s);
                fb = *(const float4*)(feat + (size_t)gr * DD + dblk_s + 4);
            }
            float4 s0 = *(const float4*)(sigw + dblk_s);
            float4 s1 = *(const float4*)(sigw + dblk_s + 4);
            f16x8 kr;
            kr[0] = (f16)(fa.x * s0.x * in); kr[1] = (f16)(fa.y * s0.y * in);
            kr[2] = (f16)(fa.z * s0.z * in); kr[3] = (f16)(fa.w * s0.w * in);
            kr[4] = (f16)(fb.x * s1.x * in); kr[5] = (f16)(fb.y * s1.y * in);
            kr[6] = (f16)(fb.z * s1.z * in); kr[7] = (f16)(fb.w * s1.w * in);
            *(f16x8*)&Kf[mloc * KS + dblk_s] = kr;
            vv[pi][0] = (f16)fa.x; vv[pi][1] = (f16)fa.y; vv[pi][2] = (f16)fa.z; vv[pi][3] = (f16)fa.w;
            vv[pi][4] = (f16)fb.x; vv[pi][5] = (f16)fb.y; vv[pi][6] = (f16)fb.z; vv[pi][7] = (f16)fb.w;
        }
        #pragma unroll
        for (int i = 0; i < 8; i++)
            *(unsigned*)&Vt[(dblk_s + i) * KS + mrow_s] = pk2(vv[0][i], vv[1][i]);
        __syncthreads();

        // ---- phase1: S^T tile (m-rows mt*32.., n-cols nt*32..) ----
        f32x16 c1;
        #pragma unroll
        for (int i = 0; i < 16; i++) c1[i] = 0.f;
        #pragma unroll
        for (int ks = 0; ks < 4; ks++) {
            f16x8 af = *(const f16x8*)&Kf[(mt * 32 + l31) * KS + ks * 16 + 8 * lh];
            c1 = __builtin_amdgcn_mfma_f32_32x32x16_f16(af, qf[ks], c1, 0, 0, 0);
        }
        // write S_lds[n][m]: C rows are m-runs of 4 -> b64
        #pragma unroll
        for (int g = 0; g < 4; g++) {
            union { f16 h[4]; uint2 u; } p;
            p.h[0] = (f16)c1[4 * g + 0]; p.h[1] = (f16)c1[4 * g + 1];
            p.h[2] = (f16)c1[4 * g + 2]; p.h[3] = (f16)c1[4 * g + 3];
            *(uint2*)&Sl[(nt * 32 + l31) * KS + mt * 32 + 8 * g + 4 * lh] = p.u;
        }
        __syncthreads();

        // ---- phase2: acc(n-block nt, d-block mt) += S . V ----
        #pragma unroll
        for (int ms = 0; ms < 4; ms++) {
            f16x8 sa = *(const f16x8*)&Sl[(nt * 32 + l31) * KS + ms * 16 + 8 * lh];
            f16x8 vb = *(const f16x8*)&Vt[(mt * 32 + l31) * KS + ms * 16 + 8 * lh];
            acc = __builtin_amdgcn_mfma_f32_32x32x16_f16(sa, vb, acc, 0, 0, 0);
        }
    }

    __syncthreads();
    float* ob = agg + (size_t)(b * T2C + t2) * NN * DD;
    int dcol = mt * 32 + l31;
    #pragma unroll
    for (int g = 0; g < 4; g++) {
        #pragma unroll
        for (int i = 0; i < 4; i++) {
            int rl = nt * 32 + 8 * g + 4 * lh + i;
            int n = n0 + rl;
            if (n < NN) {
                float dg = degs[rl];
                float dinv = (dg == 0.f) ? 0.f : 1.f / dg;
                ob[(size_t)n * DD + dcol] = acc[4 * g + i] * dinv;
            }
        }
    }
}

// ---------------------------------------------------------------------------
// k_ffn (MFMA fp16) with per-row power-of-2 scaling (overflow-proof):
//   s_n = 2^-e so max|agg_n * s_n| in (0.5, 1]
//   h_s = relu(A_s w1 + s_n b1) = s_n * h   (exact: relu pos-homogeneous)
//   o   = (h_s w2) / s_n + b2   (fp32 epilogue), + residual + LayerNorm
// ---------------------------------------------------------------------------
__global__ __launch_bounds__(256) void k_ffn(const float* __restrict__ aggin,
                                             const float* __restrict__ feat,
                                             const float* __restrict__ w1,
                                             const float* __restrict__ b1,
                                             const float* __restrict__ w2,
                                             const float* __restrict__ b2,
                                             const float* __restrict__ gamma,
                                             const float* __restrict__ beta,
                                             float* __restrict__ out) {
    __shared__ f16 Al[64 * KS];    // a_scaled [row][k]
    __shared__ f16 W1t[64 * KS];   // w1^T [n][k]
    __shared__ f16 W2t[64 * KS];
    __shared__ f16 Hl[64 * KS];    // h_s [row][hcol]
    __shared__ float Ol[64 * 68];  // o_s [row][col] fp32
    __shared__ float red[64][4][2];
    __shared__ float rmax[64][4];
    __shared__ float scls[64];     // s_n
    __shared__ float isls[64];     // 1/s_n (exact pow2)

    int tid = threadIdx.x;
    int wv = tid >> 6, lane = tid & 63;
    int l31 = lane & 31, lh = lane >> 5;
    int row0 = blockIdx.x * 64;
    int r = tid >> 2, q = tid & 3, c0 = q * 16;

    // ---- read agg fp32, per-row absmax ----
    float av[16];
    {
        const float4* src = (const float4*)(aggin + (size_t)(row0 + r) * DD + c0);
        float mx = 0.f;
        #pragma unroll
        for (int i = 0; i < 4; i++) {
            float4 f = src[i];
            av[4 * i + 0] = f.x; av[4 * i + 1] = f.y;
            av[4 * i + 2] = f.z; av[4 * i + 3] = f.w;
            mx = fmaxf(mx, fmaxf(fmaxf(fabsf(f.x), fabsf(f.y)),
                                 fmaxf(fabsf(f.z), fabsf(f.w))));
        }
        rmax[r][q] = mx;
    }
    // ---- stage W1t/W2t transposed via k-pair half2 writes ----
    {
        int k0 = (tid & 31) * 2, nb = (tid >> 5) * 8;
        #pragma unroll
        for (int i = 0; i < 2; i++) {
            float4 ra = *(const float4*)(w1 + (size_t)k0 * DD + nb + 4 * i);
            float4 rb = *(const float4*)(w1 + (size_t)(k0 + 1) * DD + nb + 4 * i);
            *(unsigned*)&W1t[(nb + 4 * i + 0) * KS + k0] = pk2((f16)ra.x, (f16)rb.x);
            *(unsigned*)&W1t[(nb + 4 * i + 1) * KS + k0] = pk2((f16)ra.y, (f16)rb.y);
            *(unsigned*)&W1t[(nb + 4 * i + 2) * KS + k0] = pk2((f16)ra.z, (f16)rb.z);
            *(unsigned*)&W1t[(nb + 4 * i + 3) * KS + k0] = pk2((f16)ra.w, (f16)rb.w);
            float4 rc = *(const float4*)(w2 + (size_t)k0 * DD + nb + 4 * i);
            float4 rd = *(const float4*)(w2 + (size_t)(k0 + 1) * DD + nb + 4 * i);
            *(unsigned*)&W2t[(nb + 4 * i + 0) * KS + k0] = pk2((f16)rc.x, (f16)rd.x);
            *(unsigned*)&W2t[(nb + 4 * i + 1) * KS + k0] = pk2((f16)rc.y, (f16)rd.y);
            *(unsigned*)&W2t[(nb + 4 * i + 2) * KS + k0] = pk2((f16)rc.z, (f16)rd.z);
            *(unsigned*)&W2t[(nb + 4 * i + 3) * KS + k0] = pk2((f16)rc.w, (f16)rd.w);
        }
    }
    __syncthreads();

    // ---- per-row pow2 scale; stage A_s fp16 ----
    {
        float rm = fmaxf(fmaxf(rmax[r][0], rmax[r][1]), fmaxf(rmax[r][2], rmax[r][3]));
        int e = 0;
        frexpf(rm, &e);                       // rm = m*2^e, m in [0.5,1)
        float scl = (rm > 1.f) ? exp2f((float)-e) : 1.f;
        if (q == 0) { scls[r] = scl; isls[r] = (rm > 1.f) ? exp2f((float)e) : 1.f; }
        #pragma unroll
        for (int i = 0; i < 2; i++) {
            f16x8 v;
            #pragma unroll
            for (int j = 0; j < 8; j++) v[j] = (f16)(av[8 * i + j] * scl);
            *(f16x8*)&Al[r * KS + c0 + 8 * i] = v;
        }
    }
    __syncthreads();

    int ct = wv & 1, rt = wv >> 1;   // tile: cols ct*32.., rows rt*32..

    // phase A: h_s^T tile = w1^T . A_s^T  (D[hcol][arow])
    f32x16 hc;
    #pragma unroll
    for (int i = 0; i < 16; i++) hc[i] = 0.f;
    #pragma unroll
    for (int ks = 0; ks < 4; ks++) {
        f16x8 af = *(const f16x8*)&W1t[(ct * 32 + l31) * KS + ks * 16 + 8 * lh];
        f16x8 bf = *(const f16x8*)&Al[(rt * 32 + l31) * KS + ks * 16 + 8 * lh];
        hc = __builtin_amdgcn_mfma_f32_32x32x16_f16(af, bf, hc, 0, 0, 0);
    }
    {
        float sA = scls[rt * 32 + l31];   // scale of this lane's a-row (D col)
        #pragma unroll
        for (int g = 0; g < 4; g++) {
            union { f16 h[4]; uint2 u; } p;
            #pragma unroll
            for (int i = 0; i < 4; i++) {
                int hcol = ct * 32 + 8 * g + 4 * lh + i;
                p.h[i] = (f16)fmaxf(hc[4 * g + i] + sA * b1[hcol], 0.f);
            }
            *(uint2*)&Hl[(rt * 32 + l31) * KS + ct * 32 + 8 * g + 4 * lh] = p.u;
        }
    }
    __syncthreads();

    // phase B: o_s^T tile = w2^T . h_s^T
    f32x16 oc;
    #pragma unroll
    for (int i = 0; i < 16; i++) oc[i] = 0.f;
    #pragma unroll
    for (int ks = 0; ks < 4; ks++) {
        f16x8 af = *(const f16x8*)&W2t[(ct * 32 + l31) * KS + ks * 16 + 8 * lh];
        f16x8 bf = *(const f16x8*)&Hl[(rt * 32 + l31) * KS + ks * 16 + 8 * lh];
        oc = __builtin_amdgcn_mfma_f32_32x32x16_f16(af, bf, oc, 0, 0, 0);
    }
    #pragma unroll
    for (int g = 0; g < 4; g++) {
        float4 o4 = make_float4(oc[4 * g + 0], oc[4 * g + 1], oc[4 * g + 2], oc[4 * g + 3]);
        *(float4*)&Ol[(rt * 32 + l31) * 68 + ct * 32 + 8 * g + 4 * lh] = o4;
    }
    __syncthreads();

    // epilogue: s = o_s/s_n + b2 + feat_residual; LayerNorm
    size_t grow = row0 + r;
    int n = (int)(grow % NN);
    int bt = (int)(grow / NN);
    int t2 = bt % T2C, bb = bt / T2C;
    size_t frow = (size_t)(bb * TT + t2 + 2) * NN + n;
    float is = isls[r];
    float v[16];
    float sum = 0.f;
    #pragma unroll
    for (int i = 0; i < 16; i++) {
        int c = c0 + i;
        float x = Ol[r * 68 + c] * is + b2[c] + feat[frow * DD + c];
        v[i] = x; sum += x;
    }
    red[r][q][0] = sum;
    __syncthreads();
    float mu = (red[r][0][0] + red[r][1][0] + red[r][2][0] + red[r][3][0]) * (1.f / 64.f);
    float s2 = 0.f;
    #pragma unroll
    for (int i = 0; i < 16; i++) { float d = v[i] - mu; s2 += d * d; }
    red[r][q][1] = s2;
    __syncthreads();
    float var = (red[r][0][1] + red[r][1][1] + red[r][2][1] + red[r][3][1]) * (1.f / 64.f);
    float rs = rsqrtf(var + 1e-5f);
    #pragma unroll
    for (int i4 = 0; i4 < 4; i4++) {
        int c = c0 + 4 * i4;
        float4 g4 = *(const float4*)(gamma + c);
        float4 be = *(const float4*)(beta + c);
        float4 o4;
        o4.x = (v[4 * i4 + 0] - mu) * rs * g4.x + be.x;
        o4.y = (v[4 * i4 + 1] - mu) * rs * g4.y + be.y;
        o4.z = (v[4 * i4 + 2] - mu) * rs * g4.z + be.z;
        o4.w = (v[4 * i4 + 3] - mu) * rs * g4.w + be.w;
        *(float4*)(out + grow * DD + c) = o4;
    }
}

// ---------------------------------------------------------------------------
extern "C" void kernel_launch(void* const* d_in, const int* in_sizes, int n_in,
                              void* d_out, int out_size, void* d_ws, size_t ws_size,
                              hipStream_t stream) {
    const float* feat    = (const float*)d_in[0];
    const float* weights = (const float*)d_in[1];
    const float* w1      = (const float*)d_in[2];
    const float* b1      = (const float*)d_in[3];
    const float* w2      = (const float*)d_in[4];
    const float* b2      = (const float*)d_in[5];
    const float* gamma   = (const float*)d_in[6];
    const float* beta    = (const float*)d_in[7];
    float* out = (float*)d_out;

    float* sigw = (float*)d_ws;            // 64
    float* invn = sigw + 64;               // 57600
    float* tsum = invn + BB * TT * NN;     // 192*64

    hipMemsetAsync(tsum, 0, (size_t)BB * TT * DD * sizeof(float), stream);
    k_prep<<<BB * TT * 5, 256, 0, stream>>>(feat, weights, sigw, invn, tsum);
    k_agg<<<NW * 5, 256, 0, stream>>>(feat, sigw, invn, tsum, out);
    k_ffn<<<(BB * T2C * NN) / 64, 256, 0, stream>>>(out, feat, w1, b1, w2, b2,
                                                    gamma, beta, out);
}